// Round 3
// baseline (1581.633 us; speedup 1.0000x reference)
//
#include <hip/hip_runtime.h>
#include <hip/hip_bf16.h>

typedef unsigned short u16;
typedef unsigned int u32;
typedef short short8 __attribute__((ext_vector_type(8)));
typedef u16 u16x8 __attribute__((ext_vector_type(8)));
typedef float f32x16 __attribute__((ext_vector_type(16)));

#define HD 2880          // H == I == 2880
#define GUN 5760         // 2*I
#define NEXP 8
#define NTOK 1024
#define NASSIGN 4096     // T*K
#define MAXPAD 5120      // 4096 + 8*127 rounded up
#define MAXTILES 40
#define SROWS 90         // 2880/32

// ---------------- global -> LDS direct staging (16B per lane) ----------------
__device__ __forceinline__ void gll16(const u16* g, u16* l) {
  __builtin_amdgcn_global_load_lds(
      (const __attribute__((address_space(1))) u32*)(const void*)g,
      (__attribute__((address_space(3))) u32*)(void*)l, 16, 0, 0);
}

// ---------------- exact mxfp4 quant helpers ----------------
__device__ __forceinline__ float quant_one(float v, float inv_scale, float scale) {
  float x = v * inv_scale;
  float a = fabsf(x);
  int n;
  if (x > 0.f)
    n = (a > 0.25f) + (a > 0.75f) + (a > 1.25f) + (a > 1.75f) +
        (a > 2.5f)  + (a > 3.5f)  + (a > 5.f);
  else
    n = (a >= 0.25f) + (a >= 0.75f) + (a >= 1.25f) + (a >= 1.75f) +
        (a >= 2.5f)  + (a >= 3.5f)  + (a >= 5.f);
  float mag = 0.5f * (float)n + 0.5f * fmaxf((float)(n - 4), 0.f) + (n == 7 ? 1.f : 0.f);
  float q = mag * scale;
  return x > 0.f ? q : (x < 0.f ? -q : 0.f);
}

__device__ __forceinline__ void make_scale(float amax, float& scale, float& inv) {
  u32 eb = (__float_as_uint(amax) >> 23) & 255u;
  scale = __uint_as_float((eb - 2u) << 23);
  inv   = __uint_as_float((256u - eb) << 23);
}

__device__ __forceinline__ u16 f2b(float f) {
  return (u16)(__float_as_uint(f) >> 16);
}

// ---------------- routing ----------------
__global__ __launch_bounds__(256)
void route_k(const int* __restrict__ ridx, const float* __restrict__ rw,
             int* __restrict__ tt_e, int* __restrict__ tt_row0, int* __restrict__ tt_rows,
             int* __restrict__ atok, float* __restrict__ awt) {
  __shared__ int cnt[NEXP], cur[NEXP], poff[NEXP];
  int tid = threadIdx.x;
  if (tid < NEXP) { cnt[tid] = 0; cur[tid] = 0; }
  __syncthreads();
  for (int a = tid; a < NASSIGN; a += 256) atomicAdd(&cnt[ridx[a]], 1);
  __syncthreads();
  if (tid == 0) {
    int off = 0, nt = 0;
    for (int e = 0; e < NEXP; ++e) {
      poff[e] = off;
      int cc = cnt[e];
      int ntl = (cc + 127) >> 7;
      for (int i = 0; i < ntl; ++i) {
        int rem = cc - i * 128;
        tt_e[nt] = e; tt_row0[nt] = off + i * 128; tt_rows[nt] = rem < 128 ? rem : 128;
        ++nt;
      }
      off += ntl * 128;
    }
    for (; nt < 64; ++nt) { tt_e[nt] = 0; tt_row0[nt] = 0; tt_rows[nt] = 0; }
  }
  __syncthreads();
  for (int r2 = tid; r2 < MAXPAD; r2 += 256) { atok[r2] = 0; awt[r2] = 0.f; }
  __syncthreads();
  for (int a = tid; a < NASSIGN; a += 256) {
    int e = ridx[a];
    int p = atomicAdd(&cur[e], 1);
    int r2 = poff[e] + p;
    atok[r2] = a >> 2;
    awt[r2] = rw[a];
  }
}

// ---------------- activation quant: x -> bf16 xq ----------------
__global__ __launch_bounds__(384)
void quant_x_k(const float* __restrict__ x, u16* __restrict__ xq) {
  int t = blockIdx.x;
  int tid = threadIdx.x;
  if (tid >= 360) return;       // 360*8 = 2880
  const float* xp = x + (long)t * HD + tid * 8;
  float4 v0 = *reinterpret_cast<const float4*>(xp);
  float4 v1 = *reinterpret_cast<const float4*>(xp + 4);
  float vv[8] = {v0.x, v0.y, v0.z, v0.w, v1.x, v1.y, v1.z, v1.w};
  float am = 0.f;
#pragma unroll
  for (int j = 0; j < 8; ++j) am = fmaxf(am, fabsf(vv[j]));
  am = fmaxf(am, __shfl_xor(am, 1));
  am = fmaxf(am, __shfl_xor(am, 2));
  u16x8 o;
  if (am > 0.f) {
    float scale, inv;
    make_scale(am, scale, inv);
#pragma unroll
    for (int j = 0; j < 8; ++j) o[j] = f2b(quant_one(vv[j], inv, scale));
  } else {
#pragma unroll
    for (int j = 0; j < 8; ++j) o[j] = 0;
  }
  *reinterpret_cast<u16x8*>(xq + (long)t * HD + tid * 8) = o;
}

// ---------------- weight dequant-transpose: codes[e][h][f] -> wT[e][f][h] bf16 ----
// 64 h per thread -> 128B contiguous stores (full cache lines, no write amplification)
__global__ __launch_bounds__(320)
void repack_k(const int* __restrict__ codes, const int* __restrict__ scales,
              u16* __restrict__ wT, int ND) {
  const int f = blockIdx.x * 320 + threadIdx.x;
  const int hb2 = blockIdx.y;   // 64-row block of h
  const int e = blockIdx.z;
  const long cbase = ((long)e * HD + hb2 * 64) * ND + f;
  const int s0 = scales[((long)e * SROWS + hb2 * 2) * ND + f];
  const int s1 = scales[((long)e * SROWS + hb2 * 2 + 1) * ND + f];
  const u32 eb0 = (u32)(s0 + 114) << 7;
  const u32 eb1 = (u32)(s1 + 114) << 7;
  u16x8 vv[8];
#pragma unroll
  for (int h = 0; h < 64; ++h) {
    u32 c = (u32)codes[cbase + (long)h * ND];
    u32 ebase = (h < 32) ? eb0 : eb1;
    u32 lo = c & 7u;
    u32 b = lo ? (ebase + (lo << 6) - (lo == 1u ? 64u : 0u)) : 0u;
    b |= (c & 8u) << 12;
    vv[h >> 3][h & 7] = (u16)b;
  }
  u16* dst = wT + ((long)e * ND + f) * HD + hb2 * 64;
#pragma unroll
  for (int i = 0; i < 8; ++i)
    *reinterpret_cast<u16x8*>(dst + i * 8) = vv[i];
}

// ---------------- bf16 MFMA GEMM, double-buffered + counted vmcnt ----------------
// BM=128, BK=64; WGM x WGN waves, per-wave frags MF x NF of 32x32x16 MFMA.
// Loads for tile t+1 are issued BEFORE computing tile t and stay in flight
// across both barriers (s_waitcnt vmcnt(VN), never 0 in steady state).
template<int BN, int WGM, int WGN, bool IS_GU>
__global__ __launch_bounds__(64 * WGM * WGN)
void moe_gemm(const u16* __restrict__ Asrc,
              const u16* __restrict__ wT,
              const float* __restrict__ bias,
              const int* __restrict__ tt_e,
              const int* __restrict__ tt_row0,
              const int* __restrict__ tt_rows,
              const int* __restrict__ atok,
              const float* __restrict__ awt,
              u16* __restrict__ gq,
              float* __restrict__ out) {
  constexpr int NWT = WGM * WGN;
  constexpr int NT = 64 * NWT;
  constexpr int ND = IS_GU ? GUN : HD;
  constexpr int MF = 128 / (32 * WGM);
  constexpr int NF = BN / (32 * WGN);
  constexpr int WMS = MF * 32;       // per-wave m span
  constexpr int WNS = NF * 32;       // per-wave n span
  constexpr int AI = (128 * 8) / NT; // A 16B-chunks per thread (exact)
  constexpr int BI = (BN * 8) / NT;  // B 16B-chunks per thread (exact)
  constexpr int VN = AI + BI;        // vmem ops per stage per thread
  constexpr int KS = 45;
  static_assert((128 * 8) % NT == 0 && (BN * 8) % NT == 0, "uniform staging");

  // XCD-chunked bijective swizzle, m-tile fastest (per-expert B-panel L2 reuse)
  int nb = gridDim.x * gridDim.y;
  int lin = blockIdx.x + gridDim.x * blockIdx.y;
  int q_ = nb >> 3, r_ = nb & 7;
  int xcd = lin & 7, pos = lin >> 3;
  int L = (xcd < r_ ? xcd * (q_ + 1) : r_ * (q_ + 1) + (xcd - r_) * q_) + pos;
  int mt = L % (int)gridDim.x;
  int nt = L / (int)gridDim.x;

  const int rows = tt_rows[mt];
  if (rows <= 0) return;
  const int e = tt_e[mt];
  const int row0 = tt_row0[mt];
  const int tid = threadIdx.x;
  const int lane = tid & 63;
  const int wid = tid >> 6;
  const int wm = wid % WGM;
  const int wn = wid / WGM;

  __shared__ __align__(16) u16 Ab[2][128 * 64];  // [m][k], chunk c at ((c^(m&7))<<3)
  __shared__ __align__(16) u16 Bb[2][BN * 64];   // [n][k], same swizzle

  // staging sources; LDS dest LINEAR, XOR swizzle pre-applied on GLOBAL source
  const u16* asrc[AI];
#pragma unroll
  for (int i = 0; i < AI; ++i) {
    int q = tid + i * NT;
    int m = q >> 3, cl = q & 7, cg = cl ^ (m & 7);
    long rowbase = IS_GU ? (long)atok[row0 + m] * HD : (long)(row0 + m) * HD;
    asrc[i] = Asrc + rowbase + cg * 8;
  }
  const u16* bsrc[BI];
#pragma unroll
  for (int i = 0; i < BI; ++i) {
    int q = tid + i * NT;
    int n = q >> 3, cl = q & 7, cg = cl ^ (n & 7);
    bsrc[i] = wT + ((long)e * ND + (long)nt * BN + n) * HD + cg * 8;
  }

  auto stage = [&](int buf, int ks) {
    const int ko = ks * 64;
#pragma unroll
    for (int i = 0; i < AI; ++i) gll16(asrc[i] + ko, &Ab[buf][(tid + i * NT) * 8]);
#pragma unroll
    for (int i = 0; i < BI; ++i) gll16(bsrc[i] + ko, &Bb[buf][(tid + i * NT) * 8]);
  };

  stage(0, 0);   // prologue: tile 0 in flight

  f32x16 acc[MF][NF];
#pragma unroll
  for (int a_ = 0; a_ < MF; ++a_)
#pragma unroll
    for (int b_ = 0; b_ < NF; ++b_)
#pragma unroll
      for (int k_ = 0; k_ < 16; ++k_) acc[a_][b_][k_] = 0.f;

  const int ml = lane & 31;
  for (int ks = 0; ks < KS; ++ks) {
    const int cur = ks & 1;
    if (ks + 1 < KS) {
      stage(cur ^ 1, ks + 1);               // issue next tile (stays in flight)
      if constexpr (VN == 4) asm volatile("s_waitcnt vmcnt(4)" ::: "memory");
      else if constexpr (VN == 5) asm volatile("s_waitcnt vmcnt(5)" ::: "memory");
      else asm volatile("s_waitcnt vmcnt(0)" ::: "memory");
    } else {
      asm volatile("s_waitcnt vmcnt(0)" ::: "memory");
    }
    __builtin_amdgcn_s_barrier();           // current tile fully staged (all waves)
    __builtin_amdgcn_sched_barrier(0);

    const u16* Abc = Ab[cur];
    const u16* Bbc = Bb[cur];
#pragma unroll
    for (int kk = 0; kk < 4; ++kk) {
      const int chunk = kk * 2 + (lane >> 5);
      short8 af[MF], bf[NF];
#pragma unroll
      for (int mf = 0; mf < MF; ++mf) {
        int m = wm * WMS + mf * 32 + ml;
        af[mf] = *reinterpret_cast<const short8*>(&Abc[m * 64 + ((chunk ^ (m & 7)) << 3)]);
      }
#pragma unroll
      for (int nf = 0; nf < NF; ++nf) {
        int n = wn * WNS + nf * 32 + ml;
        bf[nf] = *reinterpret_cast<const short8*>(&Bbc[n * 64 + ((chunk ^ (n & 7)) << 3)]);
      }
#pragma unroll
      for (int mf = 0; mf < MF; ++mf)
#pragma unroll
        for (int nf = 0; nf < NF; ++nf)
          acc[mf][nf] = __builtin_amdgcn_mfma_f32_32x32x16_bf16(af[mf], bf[nf], acc[mf][nf], 0, 0, 0);
    }

    __builtin_amdgcn_s_barrier();           // reads done before buffer reuse
    asm volatile("" ::: "memory");
  }

  // ---- epilogues (data layout identical to verified round-2 code) ----
  const int hlf = lane >> 5;
  if constexpr (IS_GU) {
    static_assert(NF == 2, "GU requant needs 64-col wave span");
#pragma unroll
    for (int mf = 0; mf < MF; ++mf) {
      float gated[2][16];
      bool evenl = ((lane & 1) == 0);
#pragma unroll
      for (int nf = 0; nf < 2; ++nf) {
        int flc = wn * WNS + nf * 32 + ml;
        int fgc = nt * BN + flc;
        float bown = bias[e * GUN + fgc];
#pragma unroll
        for (int rr = 0; rr < 16; ++rr) {
          float z = acc[mf][nf][rr] + bown;
          float zp = __shfl_xor(z, 1);
          float g = evenl ? z : zp;
          float u = evenl ? zp : z;
          g = fminf(g, 7.f);
          u = fminf(fmaxf(u, -7.f), 7.f);
          float sg = 1.f / (1.f + expf(-1.702f * g));
          gated[nf][rr] = (u + 1.f) * (g * sg);
        }
      }
#pragma unroll
      for (int rr = 0; rr < 16; ++rr) {
        float am = fmaxf(fabsf(gated[0][rr]), fabsf(gated[1][rr]));
        am = fmaxf(am, __shfl_xor(am, 2));
        am = fmaxf(am, __shfl_xor(am, 4));
        am = fmaxf(am, __shfl_xor(am, 8));
        am = fmaxf(am, __shfl_xor(am, 16));
        int mrow = (rr & 3) + 8 * (rr >> 2) + 4 * hlf;
        int rloc = wm * WMS + mf * 32 + mrow;
        u16 o0 = 0, o1 = 0;
        if (am > 0.f) {
          float scale, inv;
          make_scale(am, scale, inv);
          o0 = f2b(quant_one(gated[0][rr], inv, scale));
          o1 = f2b(quant_one(gated[1][rr], inv, scale));
        }
        if (rloc < rows && (lane & 1) == 0) {
          long rg = row0 + rloc;
          int ig = (nt * BN + wn * WNS) / 2 + (ml >> 1);
          gq[rg * HD + ig] = o0;
          gq[rg * HD + ig + 16] = o1;
        }
      }
    }
  } else {
#pragma unroll
    for (int mf = 0; mf < MF; ++mf) {
#pragma unroll
      for (int rr = 0; rr < 16; ++rr) {
        int mrow = (rr & 3) + 8 * (rr >> 2) + 4 * hlf;
        int rloc = wm * WMS + mf * 32 + mrow;
        if (rloc >= rows) continue;
        int rg = row0 + rloc;
        float wgt = awt[rg];
        long tok = atok[rg];
#pragma unroll
        for (int nf = 0; nf < NF; ++nf) {
          int hg = nt * BN + wn * WNS + nf * 32 + ml;
          float v = (acc[mf][nf][rr] + bias[e * HD + hg]) * wgt;
          atomicAdd(&out[tok * HD + hg], v);
        }
      }
    }
  }
}

// ---------------- launcher ----------------
extern "C" void kernel_launch(void* const* d_in, const int* in_sizes, int n_in,
                              void* d_out, int out_size, void* d_ws, size_t ws_size,
                              hipStream_t stream) {
  (void)in_sizes; (void)n_in; (void)ws_size;
  const float* x   = (const float*)d_in[0];
  const int* ridx  = (const int*)d_in[1];
  const float* rw  = (const float*)d_in[2];
  const int* guc   = (const int*)d_in[3];
  const int* gus   = (const int*)d_in[4];
  const float* gub = (const float*)d_in[5];
  const int* dnc   = (const int*)d_in[6];
  const int* dns   = (const int*)d_in[7];
  const float* dnb = (const float*)d_in[8];
  float* out = (float*)d_out;
  char* ws = (char*)d_ws;

  // ws layout: routing (64KB) | xq (5.9MB) | gq (29.5MB) | wT (265.4MB) ~= 288MB
  int* tt_e    = (int*)(ws);
  int* tt_row0 = (int*)(ws + 1024);
  int* tt_rows = (int*)(ws + 2048);
  int* atok    = (int*)(ws + 4096);
  float* awt   = (float*)(ws + 4096 + MAXPAD * 4);
  u16* xq      = (u16*)(ws + 65536);
  u16* gq      = (u16*)(ws + 65536 + (size_t)NTOK * HD * 2);
  u16* wT      = (u16*)(ws + 65536 + (size_t)NTOK * HD * 2 + (size_t)MAXPAD * HD * 2);

  hipMemsetAsync(d_out, 0, (size_t)out_size * sizeof(float), stream);
  route_k<<<1, 256, 0, stream>>>(ridx, rw, tt_e, tt_row0, tt_rows, atok, awt);
  quant_x_k<<<NTOK, 384, 0, stream>>>(x, xq);
  repack_k<<<dim3(GUN / 320, SROWS / 2, NEXP), 320, 0, stream>>>(guc, gus, wT, GUN);
  moe_gemm<128, 4, 2, true><<<dim3(MAXTILES, 45), 512, 0, stream>>>(
      xq, wT, gub, tt_e, tt_row0, tt_rows, atok, awt, gq, nullptr);
  repack_k<<<dim3(HD / 320, SROWS / 2, NEXP), 320, 0, stream>>>(dnc, dns, wT, HD);
  moe_gemm<192, 4, 2, false><<<dim3(MAXTILES, 15), 512, 0, stream>>>(
      gq, wT, dnb, tt_e, tt_row0, tt_rows, atok, awt, nullptr, out);
}

// Round 4
// 550.094 us; speedup vs baseline: 2.8752x; 2.8752x over previous
//
#include <hip/hip_runtime.h>
#include <hip/hip_bf16.h>

typedef unsigned char u8;
typedef unsigned short u16;
typedef unsigned int u32;
typedef int i32x4 __attribute__((ext_vector_type(4)));
typedef int i32x8 __attribute__((ext_vector_type(8)));
typedef float f32x16 __attribute__((ext_vector_type(16)));

#define HD 2880          // H == I == 2880
#define GUN 5760         // 2*I
#define NEXP 8
#define NTOK 1024
#define NASSIGN 4096     // T*K
#define MAXPAD 5120      // padded routed rows
#define MAXTILES 40
#define SROWS 90         // 2880/32
#define RB 1440          // packed fp4 row bytes (2880/2)
#define SB 96            // padded scale row bytes (90 -> 96)

// ---------------- global -> LDS direct staging (16B per lane) ----------------
__device__ __forceinline__ void gll16(const void* g, void* l) {
  __builtin_amdgcn_global_load_lds(
      (const __attribute__((address_space(1))) u32*)g,
      (__attribute__((address_space(3))) u32*)l, 16, 0, 0);
}

// ---------------- exact mxfp4 code helpers ----------------
// code = e2m1 nibble replicating LEVELS[searchsorted(MIDS, x)] exactly
__device__ __forceinline__ int quant_code(float v, float inv) {
  float x = v * inv;
  float a = fabsf(x);
  int n;
  if (x > 0.f)
    n = (a > 0.25f) + (a > 0.75f) + (a > 1.25f) + (a > 1.75f) +
        (a > 2.5f)  + (a > 3.5f)  + (a > 5.f);
  else
    n = (a >= 0.25f) + (a >= 0.75f) + (a >= 1.25f) + (a >= 1.75f) +
        (a >= 2.5f)  + (a >= 3.5f)  + (a >= 5.f);
  return x < 0.f ? (8 | n) : n;   // x==0 -> n==0 -> code 0
}

// ---------------- routing ----------------
__global__ __launch_bounds__(256)
void route_k(const int* __restrict__ ridx, const float* __restrict__ rw,
             int* __restrict__ tt_e, int* __restrict__ tt_row0, int* __restrict__ tt_rows,
             int* __restrict__ atok, float* __restrict__ awt) {
  __shared__ int cnt[NEXP], cur[NEXP], poff[NEXP];
  int tid = threadIdx.x;
  if (tid < NEXP) { cnt[tid] = 0; cur[tid] = 0; }
  __syncthreads();
  for (int a = tid; a < NASSIGN; a += 256) atomicAdd(&cnt[ridx[a]], 1);
  __syncthreads();
  if (tid == 0) {
    int off = 0, nt = 0;
    for (int e = 0; e < NEXP; ++e) {
      poff[e] = off;
      int cc = cnt[e];
      int ntl = (cc + 127) >> 7;
      for (int i = 0; i < ntl; ++i) {
        int rem = cc - i * 128;
        tt_e[nt] = e; tt_row0[nt] = off + i * 128; tt_rows[nt] = rem < 128 ? rem : 128;
        ++nt;
      }
      off += ntl * 128;
    }
    for (; nt < 64; ++nt) { tt_e[nt] = 0; tt_row0[nt] = 0; tt_rows[nt] = 0; }
  }
  __syncthreads();
  for (int r2 = tid; r2 < MAXPAD; r2 += 256) { atok[r2] = 0; awt[r2] = 0.f; }
  __syncthreads();
  for (int a = tid; a < NASSIGN; a += 256) {
    int e = ridx[a];
    int p = atomicAdd(&cur[e], 1);
    int r2 = poff[e] + p;
    atok[r2] = a >> 2;
    awt[r2] = rw[a];
  }
}

// ---------------- activation quant: x -> packed fp4 + e8m0 scales ----------------
__global__ __launch_bounds__(384)
void quant_x_k(const float* __restrict__ x, u8* __restrict__ xqp, u8* __restrict__ xs) {
  int t = blockIdx.x;
  int tid = threadIdx.x;
  if (tid >= 360) return;       // 360*8 = 2880
  const float* xp = x + (long)t * HD + tid * 8;
  float4 v0 = *reinterpret_cast<const float4*>(xp);
  float4 v1 = *reinterpret_cast<const float4*>(xp + 4);
  float vv[8] = {v0.x, v0.y, v0.z, v0.w, v1.x, v1.y, v1.z, v1.w};
  float am = 0.f;
#pragma unroll
  for (int j = 0; j < 8; ++j) am = fmaxf(am, fabsf(vv[j]));
  am = fmaxf(am, __shfl_xor(am, 1));
  am = fmaxf(am, __shfl_xor(am, 2));
  u32 eb = (__float_as_uint(am) >> 23) & 255u;
  float inv = __uint_as_float((256u - eb) << 23);
  u32 w = 0;
#pragma unroll
  for (int j = 0; j < 8; ++j) {
    u32 c = (am > 0.f) ? (u32)quant_code(vv[j], inv) : 0u;
    w |= c << (4 * j);          // elem 2b -> low nibble of byte b
  }
  *reinterpret_cast<u32*>(xqp + (long)t * RB + tid * 4) = w;
  if ((tid & 3) == 0)
    xs[(long)t * SB + (tid >> 2)] = (u8)(am > 0.f ? (eb - 2u) : 0u);
}

// ---------------- weight repack: int32 codes [e][h][f] -> packed fp4 wq[e][f][h/2] ----
// Block: 80 f x 4 h-blocks(32). Strided coalesced reads; LDS combine -> 64B line writes.
__global__ __launch_bounds__(320)
void repack_k(const int* __restrict__ codes, u8* __restrict__ wq, int ND) {
  __shared__ uint4 lt[80][4];
  const int tid = threadIdx.x;
  const int fl = tid % 80, hql = tid / 80;
  const int f0 = blockIdx.x * 80;
  const int hbq = blockIdx.y;
  const int e = blockIdx.z;
  const int hb = hbq * 4 + hql;
  if (hb < SROWS) {
    const long cbase = ((long)e * HD + hb * 32) * ND + f0 + fl;
    u32 w[4] = {0, 0, 0, 0};
#pragma unroll
    for (int j = 0; j < 16; ++j) {
      u32 c0 = (u32)codes[cbase + (long)(2 * j) * ND] & 15u;
      u32 c1 = (u32)codes[cbase + (long)(2 * j + 1) * ND] & 15u;
      w[j >> 2] |= (c0 | (c1 << 4)) << ((j & 3) * 8);
    }
    lt[fl][hql] = make_uint4(w[0], w[1], w[2], w[3]);
  }
  __syncthreads();
  const int row = tid >> 2, part = tid & 3;
  const int hbw = hbq * 4 + part;
  if (hbw < SROWS)
    *reinterpret_cast<uint4*>(wq + ((long)e * ND + f0 + row) * RB + hbw * 16) = lt[row][part];
}

// ---------------- scale repack: int32 scales [e][90][f] -> e8m0 wsb[e][f][96] ----
__global__ __launch_bounds__(384)
void srepack_k(const int* __restrict__ scales, u8* __restrict__ wsb, int ND) {
  const int tid = threadIdx.x;
  const int fl = tid / 6, p = tid % 6;
  const int f = blockIdx.x * 64 + fl;
  const int e = blockIdx.y;
  u32 w[4] = {0, 0, 0, 0};
#pragma unroll
  for (int j = 0; j < 16; ++j) {
    int t = p * 16 + j;
    u32 b = (t < SROWS) ? (u32)(scales[((long)e * SROWS + t) * ND + f] + 115) & 255u : 0u;
    w[j >> 2] |= b << ((j & 3) * 8);
  }
  *reinterpret_cast<uint4*>(wsb + ((long)e * ND + f) * SB + p * 16) =
      make_uint4(w[0], w[1], w[2], w[3]);
}

// ---------------- MX-fp4 MFMA GEMM, double-buffered + counted vmcnt ----------------
// BM=128, BK=64 (one 32x32x64 MFMA in K per frag). 512 thr = 8 waves (4m x 2n).
// MF=1, NF=BN/64. A,B tiles: [kc][row][16B] -> frag reads are contiguous/conflict-free.
// Scales staged once, transposed [kb][row] in LDS.
template<int BN, bool IS_GU>
__global__ __launch_bounds__(512)
void moe_gemm(const u8* __restrict__ Apay, const u8* __restrict__ Ascl,
              const u8* __restrict__ wq, const u8* __restrict__ wsb,
              const float* __restrict__ bias,
              const int* __restrict__ tt_e, const int* __restrict__ tt_row0,
              const int* __restrict__ tt_rows, const int* __restrict__ atok,
              const float* __restrict__ awt,
              u8* __restrict__ gqp, u8* __restrict__ gs,
              float* __restrict__ out) {
  constexpr int ND = IS_GU ? GUN : HD;
  constexpr int NF = BN / 64;            // 32-col frags per wave (WGN=2)
  constexpr int WNS = NF * 32;
  constexpr int TC = 256 + 2 * BN;       // total 16B chunks per K-step
  constexpr int ABYTES = 4096;           // A tile bytes (128*64/2)
  constexpr int KS = 45;

  // XCD-chunked bijective swizzle, m-tile fastest (B-panel L2 reuse)
  int nb = gridDim.x * gridDim.y;
  int lin = blockIdx.x + gridDim.x * blockIdx.y;
  int q_ = nb >> 3, r_ = nb & 7;
  int xcd = lin & 7, pos = lin >> 3;
  int L = (xcd < r_ ? xcd * (q_ + 1) : r_ * (q_ + 1) + (xcd - r_) * q_) + pos;
  int mt = L % (int)gridDim.x;
  int nt = L / (int)gridDim.x;

  const int rows = tt_rows[mt];
  if (rows <= 0) return;
  const int e = tt_e[mt];
  const int row0 = tt_row0[mt];
  const int tid = threadIdx.x;
  const int lane = tid & 63;
  const int wid = tid >> 6;
  const int wm = wid & 3;                // 4 row-waves
  const int wn = wid >> 2;               // 2 col-waves
  const int ml = lane & 31;
  const int kc = lane >> 5;

  __shared__ __align__(16) u8 Tiles[2][ABYTES + BN * 32];
  __shared__ u8 ASl[SB * 128];
  __shared__ u8 BSl[SB * BN];

  // ---- per-thread staging chunks (1 or 2), static unrolled ----
  const u8* gsrc0; int ldof0;
  const u8* gsrc1 = nullptr; int ldof1 = 0;
  {
    int c = tid;
    if (c < 256) {
      int kcc = c >> 7, row = c & 127;
      long rbase = IS_GU ? (long)atok[row0 + row] * RB : (long)(row0 + row) * RB;
      gsrc0 = Apay + rbase + kcc * 16;
      ldof0 = c * 16;
    } else {
      int qb = c - 256, kcc = qb / BN, col = qb % BN;
      gsrc0 = wq + ((long)e * ND + (long)nt * BN + col) * RB + kcc * 16;
      ldof0 = ABYTES + qb * 16;
    }
    int c2 = tid + 512;
    if (c2 < TC) {
      int qb = c2 - 256, kcc = qb / BN, col = qb % BN;
      gsrc1 = wq + ((long)e * ND + (long)nt * BN + col) * RB + kcc * 16;
      ldof1 = ABYTES + qb * 16;
    }
  }
  const bool has2 = (tid + 512) < TC;

  // ---- one-time scale staging, transposed [kb][row] ----
  for (int sc = tid; sc < 768; sc += 512) {
    int row = sc / 6, part = sc % 6;
    long rbase = IS_GU ? (long)atok[row0 + row] * SB : (long)(row0 + row) * SB;
    uint4 v = *reinterpret_cast<const uint4*>(Ascl + rbase + part * 16);
    u32 arr[4] = {v.x, v.y, v.z, v.w};
#pragma unroll
    for (int j = 0; j < 16; ++j)
      ASl[(part * 16 + j) * 128 + row] = (u8)(arr[j >> 2] >> ((j & 3) * 8));
  }
  for (int sc = tid; sc < BN * 6; sc += 512) {
    int col = sc / 6, part = sc % 6;
    uint4 v = *reinterpret_cast<const uint4*>(
        wsb + ((long)e * ND + (long)nt * BN + col) * SB + part * 16);
    u32 arr[4] = {v.x, v.y, v.z, v.w};
#pragma unroll
    for (int j = 0; j < 16; ++j)
      BSl[(part * 16 + j) * BN + col] = (u8)(arr[j >> 2] >> ((j & 3) * 8));
  }

  // prologue: tile 0
  gll16(gsrc0, &Tiles[0][ldof0]);
  if (has2) gll16(gsrc1, &Tiles[0][ldof1]);
  __syncthreads();   // scales staged + tile 0 drained

  f32x16 acc[NF];
#pragma unroll
  for (int b_ = 0; b_ < NF; ++b_)
#pragma unroll
    for (int k_ = 0; k_ < 16; ++k_) acc[b_][k_] = 0.f;

  const int arow = wm * 32 + ml;
  const int aoff = ((kc * 128 + arow) << 4);
  int boff[NF], bcol[NF];
#pragma unroll
  for (int nf = 0; nf < NF; ++nf) {
    bcol[nf] = wn * WNS + nf * 32 + ml;
    boff[nf] = ABYTES + ((kc * BN + bcol[nf]) << 4);
  }

  for (int ks = 0; ks < KS; ++ks) {
    const int cur = ks & 1;
    if (ks + 1 < KS) {
      const long ko = (long)(ks + 1) * 32;
      gll16(gsrc0 + ko, &Tiles[cur ^ 1][ldof0]);
      if (has2) gll16(gsrc1 + ko, &Tiles[cur ^ 1][ldof1]);
      if (wid < 2) {
        if constexpr (TC > 512) asm volatile("s_waitcnt vmcnt(2)" ::: "memory");
        else asm volatile("s_waitcnt vmcnt(1)" ::: "memory");
      } else {
        asm volatile("s_waitcnt vmcnt(1)" ::: "memory");
      }
    } else {
      asm volatile("s_waitcnt vmcnt(0)" ::: "memory");
    }
    __builtin_amdgcn_s_barrier();         // current tile staged on all waves
    __builtin_amdgcn_sched_barrier(0);

    const int kb = 2 * ks + kc;
    i32x4 av = *reinterpret_cast<const i32x4*>(&Tiles[cur][aoff]);
    int sa = (int)ASl[kb * 128 + arow];
    i32x8 a8 = {av[0], av[1], av[2], av[3], 0, 0, 0, 0};
#pragma unroll
    for (int nf = 0; nf < NF; ++nf) {
      i32x4 bv = *reinterpret_cast<const i32x4*>(&Tiles[cur][boff[nf]]);
      int sb = (int)BSl[kb * BN + bcol[nf]];
      i32x8 b8 = {bv[0], bv[1], bv[2], bv[3], 0, 0, 0, 0};
      acc[nf] = __builtin_amdgcn_mfma_scale_f32_32x32x64_f8f6f4(
          a8, b8, acc[nf], 4, 4, 0, sa, 0, sb);
    }

    __builtin_amdgcn_s_barrier();         // reads done before buffer reuse
    asm volatile("" ::: "memory");
  }

  // ---- epilogues ----
  const int hlf = lane >> 5;
  if constexpr (IS_GU) {
    float gated[2][16];
    bool evenl = ((lane & 1) == 0);
#pragma unroll
    for (int nf = 0; nf < 2; ++nf) {
      int fgc = nt * BN + wn * 64 + nf * 32 + ml;
      float bown = bias[e * GUN + fgc];
#pragma unroll
      for (int rr = 0; rr < 16; ++rr) {
        float z = acc[nf][rr] + bown;
        float zp = __shfl_xor(z, 1);
        float g = evenl ? z : zp;
        float u = evenl ? zp : z;
        g = fminf(g, 7.f);
        u = fminf(fmaxf(u, -7.f), 7.f);
        float sg = 1.f / (1.f + expf(-1.702f * g));
        gated[nf][rr] = (u + 1.f) * (g * sg);
      }
    }
#pragma unroll
    for (int rr = 0; rr < 16; ++rr) {
      float am = fmaxf(fabsf(gated[0][rr]), fabsf(gated[1][rr]));
      am = fmaxf(am, __shfl_xor(am, 2));
      am = fmaxf(am, __shfl_xor(am, 4));
      am = fmaxf(am, __shfl_xor(am, 8));
      am = fmaxf(am, __shfl_xor(am, 16));
      u32 eb = (__float_as_uint(am) >> 23) & 255u;
      float inv = __uint_as_float((256u - eb) << 23);
      int c0 = (am > 0.f) ? quant_code(gated[0][rr], inv) : 0;
      int c1 = (am > 0.f) ? quant_code(gated[1][rr], inv) : 0;
      int b0 = c0 | (__shfl_xor(c0, 2) << 4);   // valid at (lane&3)==0
      int b1 = c1 | (__shfl_xor(c1, 2) << 4);
      int mrow = (rr & 3) + 8 * (rr >> 2) + 4 * hlf;
      int rloc = wm * 32 + mrow;
      if (rloc < rows && (lane & 3) == 0) {
        long rg = row0 + rloc;
        int bb = nt * 32 + wn * 16 + (ml >> 2);  // byte index of gated[0] pair
        gqp[rg * RB + bb] = (u8)b0;
        gqp[rg * RB + bb + 8] = (u8)b1;
        if (ml == 0)
          gs[rg * SB + nt * 2 + wn] = (u8)(am > 0.f ? (eb - 2u) : 0u);
      }
    }
  } else {
#pragma unroll
    for (int rr = 0; rr < 16; ++rr) {
      int mrow = (rr & 3) + 8 * (rr >> 2) + 4 * hlf;
      int rloc = wm * 32 + mrow;
      if (rloc >= rows) continue;
      int rg = row0 + rloc;
      float wgt = awt[rg];
      long tok = atok[rg];
#pragma unroll
      for (int nf = 0; nf < NF; ++nf) {
        int hg = nt * BN + wn * WNS + nf * 32 + ml;
        float v = (acc[nf][rr] + bias[e * HD + hg]) * wgt;
        atomicAdd(&out[tok * HD + hg], v);
      }
    }
  }
}

// ---------------- launcher ----------------
extern "C" void kernel_launch(void* const* d_in, const int* in_sizes, int n_in,
                              void* d_out, int out_size, void* d_ws, size_t ws_size,
                              hipStream_t stream) {
  (void)in_sizes; (void)n_in; (void)ws_size;
  const float* x   = (const float*)d_in[0];
  const int* ridx  = (const int*)d_in[1];
  const float* rw  = (const float*)d_in[2];
  const int* guc   = (const int*)d_in[3];
  const int* gus   = (const int*)d_in[4];
  const float* gub = (const float*)d_in[5];
  const int* dnc   = (const int*)d_in[6];
  const int* dns   = (const int*)d_in[7];
  const float* dnb = (const float*)d_in[8];
  float* out = (float*)d_out;
  char* ws = (char*)d_ws;

  // ws layout (~116 MB)
  int* tt_e    = (int*)(ws);
  int* tt_row0 = (int*)(ws + 1024);
  int* tt_rows = (int*)(ws + 2048);
  int* atok    = (int*)(ws + 4096);
  float* awt   = (float*)(ws + 4096 + MAXPAD * 4);
  size_t off = 65536;
  u8* xqp = (u8*)(ws + off);  off += (size_t)NTOK * RB;      // 1.47 MB
  u8* xs  = (u8*)(ws + off);  off += (size_t)NTOK * SB;      // 98 KB
  u8* gqp = (u8*)(ws + off);  off += (size_t)MAXPAD * RB;    // 7.37 MB
  u8* gs  = (u8*)(ws + off);  off += (size_t)MAXPAD * SB;    // 0.49 MB
  u8* wqg = (u8*)(ws + off);  off += (size_t)NEXP * GUN * RB; // 66.4 MB
  u8* wsg = (u8*)(ws + off);  off += (size_t)NEXP * GUN * SB; // 4.4 MB
  u8* wqd = (u8*)(ws + off);  off += (size_t)NEXP * HD * RB;  // 33.2 MB
  u8* wsd = (u8*)(ws + off);  off += (size_t)NEXP * HD * SB;  // 2.2 MB

  hipMemsetAsync(d_out, 0, (size_t)out_size * sizeof(float), stream);
  route_k<<<1, 256, 0, stream>>>(ridx, rw, tt_e, tt_row0, tt_rows, atok, awt);
  quant_x_k<<<NTOK, 384, 0, stream>>>(x, xqp, xs);
  repack_k<<<dim3(GUN / 80, 23, NEXP), 320, 0, stream>>>(guc, wqg, GUN);
  srepack_k<<<dim3(GUN / 64, NEXP), 384, 0, stream>>>(gus, wsg, GUN);
  repack_k<<<dim3(HD / 80, 23, NEXP), 320, 0, stream>>>(dnc, wqd, HD);
  srepack_k<<<dim3(HD / 64, NEXP), 384, 0, stream>>>(dns, wsd, HD);
  moe_gemm<128, true><<<dim3(MAXTILES, 45), 512, 0, stream>>>(
      xqp, xs, wqg, wsg, gub, tt_e, tt_row0, tt_rows, atok, awt, gqp, gs, nullptr);
  moe_gemm<192, false><<<dim3(MAXTILES, 15), 512, 0, stream>>>(
      gqp, gs, wqd, wsd, dnb, tt_e, tt_row0, tt_rows, atok, awt, nullptr, nullptr, out);
}

// Round 5
// 548.748 us; speedup vs baseline: 2.8823x; 1.0025x over previous
//
#include <hip/hip_runtime.h>
#include <hip/hip_bf16.h>

typedef unsigned char u8;
typedef unsigned short u16;
typedef unsigned int u32;
typedef int i32x4 __attribute__((ext_vector_type(4)));
typedef int i32x8 __attribute__((ext_vector_type(8)));
typedef float f32x16 __attribute__((ext_vector_type(16)));

#define HD 2880          // H == I == 2880
#define GUN 5760         // 2*I
#define NEXP 8
#define NTOK 1024
#define NASSIGN 4096     // T*K
#define MAXPAD 5120      // padded routed rows
#define MAXTILES 40
#define SROWS 90         // 2880/32
#define RB 1440          // packed fp4 row bytes (2880/2)
#define SB 96            // padded scale row bytes (90 -> 96)

// ---------------- global -> LDS direct staging (16B per lane) ----------------
__device__ __forceinline__ void gll16(const void* g, void* l) {
  __builtin_amdgcn_global_load_lds(
      (const __attribute__((address_space(1))) u32*)g,
      (__attribute__((address_space(3))) u32*)l, 16, 0, 0);
}

// ---------------- exact mxfp4 code helpers ----------------
// code = e2m1 nibble replicating LEVELS[searchsorted(MIDS, x)] exactly
__device__ __forceinline__ int quant_code(float v, float inv) {
  float x = v * inv;
  float a = fabsf(x);
  int n;
  if (x > 0.f)
    n = (a > 0.25f) + (a > 0.75f) + (a > 1.25f) + (a > 1.75f) +
        (a > 2.5f)  + (a > 3.5f)  + (a > 5.f);
  else
    n = (a >= 0.25f) + (a >= 0.75f) + (a >= 1.25f) + (a >= 1.75f) +
        (a >= 2.5f)  + (a >= 3.5f)  + (a >= 5.f);
  return x < 0.f ? (8 | n) : n;   // x==0 -> n==0 -> code 0
}

// ---------------- fast zero for d_out (runtime fillBuffer ran at 36 GB/s) ----
__global__ __launch_bounds__(256)
void zero_k(float4* __restrict__ p, int n4) {
  int i = blockIdx.x * 256 + threadIdx.x;
  int stride = gridDim.x * 256;
  for (; i < n4; i += stride) p[i] = make_float4(0.f, 0.f, 0.f, 0.f);
}

// ---------------- routing ----------------
__global__ __launch_bounds__(256)
void route_k(const int* __restrict__ ridx, const float* __restrict__ rw,
             int* __restrict__ tt_e, int* __restrict__ tt_row0, int* __restrict__ tt_rows,
             int* __restrict__ atok, float* __restrict__ awt) {
  __shared__ int cnt[NEXP], cur[NEXP], poff[NEXP];
  int tid = threadIdx.x;
  if (tid < NEXP) { cnt[tid] = 0; cur[tid] = 0; }
  __syncthreads();
  for (int a = tid; a < NASSIGN; a += 256) atomicAdd(&cnt[ridx[a]], 1);
  __syncthreads();
  if (tid == 0) {
    int off = 0, nt = 0;
    for (int e = 0; e < NEXP; ++e) {
      poff[e] = off;
      int cc = cnt[e];
      int ntl = (cc + 127) >> 7;
      for (int i = 0; i < ntl; ++i) {
        int rem = cc - i * 128;
        tt_e[nt] = e; tt_row0[nt] = off + i * 128; tt_rows[nt] = rem < 128 ? rem : 128;
        ++nt;
      }
      off += ntl * 128;
    }
    for (; nt < 64; ++nt) { tt_e[nt] = 0; tt_row0[nt] = 0; tt_rows[nt] = 0; }
  }
  __syncthreads();
  for (int r2 = tid; r2 < MAXPAD; r2 += 256) { atok[r2] = 0; awt[r2] = 0.f; }
  __syncthreads();
  for (int a = tid; a < NASSIGN; a += 256) {
    int e = ridx[a];
    int p = atomicAdd(&cur[e], 1);
    int r2 = poff[e] + p;
    atok[r2] = a >> 2;
    awt[r2] = rw[a];
  }
}

// ---------------- activation quant: x -> packed fp4 + e8m0 scales ----------------
__global__ __launch_bounds__(384)
void quant_x_k(const float* __restrict__ x, u8* __restrict__ xqp, u8* __restrict__ xs) {
  int t = blockIdx.x;
  int tid = threadIdx.x;
  if (tid >= 360) return;       // 360*8 = 2880
  const float* xp = x + (long)t * HD + tid * 8;
  float4 v0 = *reinterpret_cast<const float4*>(xp);
  float4 v1 = *reinterpret_cast<const float4*>(xp + 4);
  float vv[8] = {v0.x, v0.y, v0.z, v0.w, v1.x, v1.y, v1.z, v1.w};
  float am = 0.f;
#pragma unroll
  for (int j = 0; j < 8; ++j) am = fmaxf(am, fabsf(vv[j]));
  am = fmaxf(am, __shfl_xor(am, 1));
  am = fmaxf(am, __shfl_xor(am, 2));
  u32 eb = (__float_as_uint(am) >> 23) & 255u;
  float inv = __uint_as_float((256u - eb) << 23);
  u32 w = 0;
#pragma unroll
  for (int j = 0; j < 8; ++j) {
    u32 c = (am > 0.f) ? (u32)quant_code(vv[j], inv) : 0u;
    w |= c << (4 * j);          // elem 2b -> low nibble of byte b
  }
  *reinterpret_cast<u32*>(xqp + (long)t * RB + tid * 4) = w;
  if ((tid & 3) == 0)
    xs[(long)t * SB + (tid >> 2)] = (u8)(am > 0.f ? (eb - 2u) : 0u);
}

// ---------------- weight repack: int32 codes [e][h][f] -> packed fp4 wq[e][f][h/2] ----
// Block: 80 f x 4 h-blocks(32). Strided coalesced reads; LDS combine -> 64B line writes.
__global__ __launch_bounds__(320)
void repack_k(const int* __restrict__ codes, u8* __restrict__ wq, int ND) {
  __shared__ uint4 lt[80][4];
  const int tid = threadIdx.x;
  const int fl = tid % 80, hql = tid / 80;
  const int f0 = blockIdx.x * 80;
  const int hbq = blockIdx.y;
  const int e = blockIdx.z;
  const int hb = hbq * 4 + hql;
  if (hb < SROWS) {
    const long cbase = ((long)e * HD + hb * 32) * ND + f0 + fl;
    u32 w[4] = {0, 0, 0, 0};
#pragma unroll
    for (int j = 0; j < 16; ++j) {
      u32 c0 = (u32)codes[cbase + (long)(2 * j) * ND] & 15u;
      u32 c1 = (u32)codes[cbase + (long)(2 * j + 1) * ND] & 15u;
      w[j >> 2] |= (c0 | (c1 << 4)) << ((j & 3) * 8);
    }
    lt[fl][hql] = make_uint4(w[0], w[1], w[2], w[3]);
  }
  __syncthreads();
  const int row = tid >> 2, part = tid & 3;
  const int hbw = hbq * 4 + part;
  if (hbw < SROWS)
    *reinterpret_cast<uint4*>(wq + ((long)e * ND + f0 + row) * RB + hbw * 16) = lt[row][part];
}

// ---------------- scale repack: int32 scales [e][90][f] -> e8m0 wsb[e][f][96] ----
__global__ __launch_bounds__(384)
void srepack_k(const int* __restrict__ scales, u8* __restrict__ wsb, int ND) {
  const int tid = threadIdx.x;
  const int fl = tid / 6, p = tid % 6;
  const int f = blockIdx.x * 64 + fl;
  const int e = blockIdx.y;
  u32 w[4] = {0, 0, 0, 0};
#pragma unroll
  for (int j = 0; j < 16; ++j) {
    int t = p * 16 + j;
    u32 b = (t < SROWS) ? (u32)(scales[((long)e * SROWS + t) * ND + f] + 115) & 255u : 0u;
    w[j >> 2] |= b << ((j & 3) * 8);
  }
  *reinterpret_cast<uint4*>(wsb + ((long)e * ND + f) * SB + p * 16) =
      make_uint4(w[0], w[1], w[2], w[3]);
}

// ---------------- MX-fp4 MFMA GEMM, double-buffered + counted vmcnt ----------------
// BM=128, BK=64 (one 32x32x64 MFMA in K per frag). 512 thr = 8 waves (4m x 2n).
// MF=1, NF=BN/64. A,B tiles: [kc][row][16B] -> frag reads are contiguous/conflict-free.
// Scales staged once, transposed [kb][row] in LDS.
template<int BN, bool IS_GU>
__global__ __launch_bounds__(512)
void moe_gemm(const u8* __restrict__ Apay, const u8* __restrict__ Ascl,
              const u8* __restrict__ wq, const u8* __restrict__ wsb,
              const float* __restrict__ bias,
              const int* __restrict__ tt_e, const int* __restrict__ tt_row0,
              const int* __restrict__ tt_rows, const int* __restrict__ atok,
              const float* __restrict__ awt,
              u8* __restrict__ gqp, u8* __restrict__ gs,
              float* __restrict__ out) {
  constexpr int ND = IS_GU ? GUN : HD;
  constexpr int NF = BN / 64;            // 32-col frags per wave (WGN=2)
  constexpr int WNS = NF * 32;
  constexpr int TC = 256 + 2 * BN;       // total 16B chunks per K-step
  constexpr int ABYTES = 4096;           // A tile bytes (128*64/2)
  constexpr int KS = 45;

  // XCD-chunked bijective swizzle, m-tile fastest (B-panel L2 reuse)
  int nb = gridDim.x * gridDim.y;
  int lin = blockIdx.x + gridDim.x * blockIdx.y;
  int q_ = nb >> 3, r_ = nb & 7;
  int xcd = lin & 7, pos = lin >> 3;
  int L = (xcd < r_ ? xcd * (q_ + 1) : r_ * (q_ + 1) + (xcd - r_) * q_) + pos;
  int mt = L % (int)gridDim.x;
  int nt = L / (int)gridDim.x;

  const int rows = tt_rows[mt];
  if (rows <= 0) return;
  const int e = tt_e[mt];
  const int row0 = tt_row0[mt];
  const int tid = threadIdx.x;
  const int lane = tid & 63;
  const int wid = tid >> 6;
  const int wm = wid & 3;                // 4 row-waves
  const int wn = wid >> 2;               // 2 col-waves
  const int ml = lane & 31;
  const int kc = lane >> 5;

  __shared__ __align__(16) u8 Tiles[2][ABYTES + BN * 32];
  __shared__ u8 ASl[SB * 128];
  __shared__ u8 BSl[SB * BN];

  // ---- per-thread staging chunks (1 or 2), static unrolled ----
  const u8* gsrc0; int ldof0;
  const u8* gsrc1 = nullptr; int ldof1 = 0;
  {
    int c = tid;
    if (c < 256) {
      int kcc = c >> 7, row = c & 127;
      long rbase = IS_GU ? (long)atok[row0 + row] * RB : (long)(row0 + row) * RB;
      gsrc0 = Apay + rbase + kcc * 16;
      ldof0 = c * 16;
    } else {
      int qb = c - 256, kcc = qb / BN, col = qb % BN;
      gsrc0 = wq + ((long)e * ND + (long)nt * BN + col) * RB + kcc * 16;
      ldof0 = ABYTES + qb * 16;
    }
    int c2 = tid + 512;
    if (c2 < TC) {
      int qb = c2 - 256, kcc = qb / BN, col = qb % BN;
      gsrc1 = wq + ((long)e * ND + (long)nt * BN + col) * RB + kcc * 16;
      ldof1 = ABYTES + qb * 16;
    }
  }
  const bool has2 = (tid + 512) < TC;

  // ---- one-time scale staging, transposed [kb][row] ----
  for (int sc = tid; sc < 768; sc += 512) {
    int row = sc / 6, part = sc % 6;
    long rbase = IS_GU ? (long)atok[row0 + row] * SB : (long)(row0 + row) * SB;
    uint4 v = *reinterpret_cast<const uint4*>(Ascl + rbase + part * 16);
    u32 arr[4] = {v.x, v.y, v.z, v.w};
#pragma unroll
    for (int j = 0; j < 16; ++j)
      ASl[(part * 16 + j) * 128 + row] = (u8)(arr[j >> 2] >> ((j & 3) * 8));
  }
  for (int sc = tid; sc < BN * 6; sc += 512) {
    int col = sc / 6, part = sc % 6;
    uint4 v = *reinterpret_cast<const uint4*>(
        wsb + ((long)e * ND + (long)nt * BN + col) * SB + part * 16);
    u32 arr[4] = {v.x, v.y, v.z, v.w};
#pragma unroll
    for (int j = 0; j < 16; ++j)
      BSl[(part * 16 + j) * BN + col] = (u8)(arr[j >> 2] >> ((j & 3) * 8));
  }

  // prologue: tile 0
  gll16(gsrc0, &Tiles[0][ldof0]);
  if (has2) gll16(gsrc1, &Tiles[0][ldof1]);
  __syncthreads();   // scales staged + tile 0 drained

  f32x16 acc[NF];
#pragma unroll
  for (int b_ = 0; b_ < NF; ++b_)
#pragma unroll
    for (int k_ = 0; k_ < 16; ++k_) acc[b_][k_] = 0.f;

  const int arow = wm * 32 + ml;
  const int aoff = ((kc * 128 + arow) << 4);
  int boff[NF], bcol[NF];
#pragma unroll
  for (int nf = 0; nf < NF; ++nf) {
    bcol[nf] = wn * WNS + nf * 32 + ml;
    boff[nf] = ABYTES + ((kc * BN + bcol[nf]) << 4);
  }

  for (int ks = 0; ks < KS; ++ks) {
    const int cur = ks & 1;
    if (ks + 1 < KS) {
      const long ko = (long)(ks + 1) * 32;
      gll16(gsrc0 + ko, &Tiles[cur ^ 1][ldof0]);
      if (has2) gll16(gsrc1 + ko, &Tiles[cur ^ 1][ldof1]);
      if (wid < 2) {
        if constexpr (TC > 512) asm volatile("s_waitcnt vmcnt(2)" ::: "memory");
        else asm volatile("s_waitcnt vmcnt(1)" ::: "memory");
      } else {
        asm volatile("s_waitcnt vmcnt(1)" ::: "memory");
      }
    } else {
      asm volatile("s_waitcnt vmcnt(0)" ::: "memory");
    }
    __builtin_amdgcn_s_barrier();         // current tile staged on all waves
    __builtin_amdgcn_sched_barrier(0);

    const int kb = 2 * ks + kc;
    i32x4 av = *reinterpret_cast<const i32x4*>(&Tiles[cur][aoff]);
    int sa = (int)ASl[kb * 128 + arow];
    i32x8 a8 = {av[0], av[1], av[2], av[3], 0, 0, 0, 0};
#pragma unroll
    for (int nf = 0; nf < NF; ++nf) {
      i32x4 bv = *reinterpret_cast<const i32x4*>(&Tiles[cur][boff[nf]]);
      int sb = (int)BSl[kb * BN + bcol[nf]];
      i32x8 b8 = {bv[0], bv[1], bv[2], bv[3], 0, 0, 0, 0};
      acc[nf] = __builtin_amdgcn_mfma_scale_f32_32x32x64_f8f6f4(
          a8, b8, acc[nf], 4, 4, 0, sa, 0, sb);
    }

    __builtin_amdgcn_s_barrier();         // reads done before buffer reuse
    asm volatile("" ::: "memory");
  }

  // ---- epilogues ----
  const int hlf = lane >> 5;
  if constexpr (IS_GU) {
    float gated[2][16];
    bool evenl = ((lane & 1) == 0);
#pragma unroll
    for (int nf = 0; nf < 2; ++nf) {
      int fgc = nt * BN + wn * 64 + nf * 32 + ml;
      float bown = bias[e * GUN + fgc];
#pragma unroll
      for (int rr = 0; rr < 16; ++rr) {
        float z = acc[nf][rr] + bown;
        float zp = __shfl_xor(z, 1);
        float g = evenl ? z : zp;
        float u = evenl ? zp : z;
        g = fminf(g, 7.f);
        u = fminf(fmaxf(u, -7.f), 7.f);
        float sg = 1.f / (1.f + expf(-1.702f * g));
        gated[nf][rr] = (u + 1.f) * (g * sg);
      }
    }
#pragma unroll
    for (int rr = 0; rr < 16; ++rr) {
      float am = fmaxf(fabsf(gated[0][rr]), fabsf(gated[1][rr]));
      am = fmaxf(am, __shfl_xor(am, 2));
      am = fmaxf(am, __shfl_xor(am, 4));
      am = fmaxf(am, __shfl_xor(am, 8));
      am = fmaxf(am, __shfl_xor(am, 16));
      u32 eb = (__float_as_uint(am) >> 23) & 255u;
      float inv = __uint_as_float((256u - eb) << 23);
      int c0 = (am > 0.f) ? quant_code(gated[0][rr], inv) : 0;
      int c1 = (am > 0.f) ? quant_code(gated[1][rr], inv) : 0;
      int b0 = c0 | (__shfl_xor(c0, 2) << 4);   // valid at (lane&3)==0
      int b1 = c1 | (__shfl_xor(c1, 2) << 4);
      int mrow = (rr & 3) + 8 * (rr >> 2) + 4 * hlf;
      int rloc = wm * 32 + mrow;
      if (rloc < rows && (lane & 3) == 0) {
        long rg = row0 + rloc;
        int bb = nt * 32 + wn * 16 + (ml >> 2);  // byte index of gated[0] pair
        gqp[rg * RB + bb] = (u8)b0;
        gqp[rg * RB + bb + 8] = (u8)b1;
        if (ml == 0)
          gs[rg * SB + nt * 2 + wn] = (u8)(am > 0.f ? (eb - 2u) : 0u);
      }
    }
  } else {
#pragma unroll
    for (int rr = 0; rr < 16; ++rr) {
      int mrow = (rr & 3) + 8 * (rr >> 2) + 4 * hlf;
      int rloc = wm * 32 + mrow;
      if (rloc >= rows) continue;
      int rg = row0 + rloc;
      float wgt = awt[rg];
      long tok = atok[rg];
#pragma unroll
      for (int nf = 0; nf < NF; ++nf) {
        int hg = nt * BN + wn * WNS + nf * 32 + ml;
        float v = (acc[nf][rr] + bias[e * HD + hg]) * wgt;
        atomicAdd(&out[tok * HD + hg], v);
      }
    }
  }
}

// ---------------- launcher ----------------
extern "C" void kernel_launch(void* const* d_in, const int* in_sizes, int n_in,
                              void* d_out, int out_size, void* d_ws, size_t ws_size,
                              hipStream_t stream) {
  (void)in_sizes; (void)n_in; (void)ws_size;
  const float* x   = (const float*)d_in[0];
  const int* ridx  = (const int*)d_in[1];
  const float* rw  = (const float*)d_in[2];
  const int* guc   = (const int*)d_in[3];
  const int* gus   = (const int*)d_in[4];
  const float* gub = (const float*)d_in[5];
  const int* dnc   = (const int*)d_in[6];
  const int* dns   = (const int*)d_in[7];
  const float* dnb = (const float*)d_in[8];
  float* out = (float*)d_out;
  char* ws = (char*)d_ws;

  // ws layout (~116 MB)
  int* tt_e    = (int*)(ws);
  int* tt_row0 = (int*)(ws + 1024);
  int* tt_rows = (int*)(ws + 2048);
  int* atok    = (int*)(ws + 4096);
  float* awt   = (float*)(ws + 4096 + MAXPAD * 4);
  size_t off = 65536;
  u8* xqp = (u8*)(ws + off);  off += (size_t)NTOK * RB;      // 1.47 MB
  u8* xs  = (u8*)(ws + off);  off += (size_t)NTOK * SB;      // 98 KB
  u8* gqp = (u8*)(ws + off);  off += (size_t)MAXPAD * RB;    // 7.37 MB
  u8* gs  = (u8*)(ws + off);  off += (size_t)MAXPAD * SB;    // 0.49 MB
  u8* wqg = (u8*)(ws + off);  off += (size_t)NEXP * GUN * RB; // 66.4 MB
  u8* wsg = (u8*)(ws + off);  off += (size_t)NEXP * GUN * SB; // 4.4 MB
  u8* wqd = (u8*)(ws + off);  off += (size_t)NEXP * HD * RB;  // 33.2 MB
  u8* wsd = (u8*)(ws + off);  off += (size_t)NEXP * HD * SB;  // 2.2 MB

  zero_k<<<720, 256, 0, stream>>>((float4*)d_out, out_size / 4);
  route_k<<<1, 256, 0, stream>>>(ridx, rw, tt_e, tt_row0, tt_rows, atok, awt);
  quant_x_k<<<NTOK, 384, 0, stream>>>(x, xqp, xs);
  repack_k<<<dim3(GUN / 80, 23, NEXP), 320, 0, stream>>>(guc, wqg, GUN);
  srepack_k<<<dim3(GUN / 64, NEXP), 384, 0, stream>>>(gus, wsg, GUN);
  repack_k<<<dim3(HD / 80, 23, NEXP), 320, 0, stream>>>(dnc, wqd, HD);
  srepack_k<<<dim3(HD / 64, NEXP), 384, 0, stream>>>(dns, wsd, HD);
  moe_gemm<128, true><<<dim3(MAXTILES, 45), 512, 0, stream>>>(
      xqp, xs, wqg, wsg, gub, tt_e, tt_row0, tt_rows, atok, awt, gqp, gs, nullptr);
  moe_gemm<192, false><<<dim3(MAXTILES, 15), 512, 0, stream>>>(
      gqp, gs, wqd, wsd, dnb, tt_e, tt_row0, tt_rows, atok, awt, nullptr, nullptr, out);
}